// Round 1
// baseline (860.123 us; speedup 1.0000x reference)
//
#include <hip/hip_runtime.h>
#include <hip/hip_bf16.h>
#include <cstdint>

// Problem constants (from reference setup_inputs)
#define NTOK 65536
#define DDIM 768
#define VOC  32000
#define SEG  8192

typedef unsigned short ushort_t;
typedef __attribute__((ext_vector_type(8))) __bf16 bf16x8;
typedef __attribute__((ext_vector_type(4))) float  f32x4;

__device__ __forceinline__ ushort_t f2bf(float f) {
  uint32_t u = __builtin_bit_cast(uint32_t, f);
  return (ushort_t)((u + 0x7fffu + ((u >> 16) & 1u)) >> 16);
}

// ---------------- f32 -> bf16 conversion (vectorized) ----------------
__global__ __launch_bounds__(256) void cvt_bf16(const float4* __restrict__ in,
                                                ushort4* __restrict__ out, int n4) {
  int i = blockIdx.x * 256 + threadIdx.x;
  if (i >= n4) return;
  float4 v = in[i];
  ushort4 o;
  o.x = f2bf(v.x); o.y = f2bf(v.y); o.z = f2bf(v.z); o.w = f2bf(v.w);
  out[i] = o;
}

// ---------------- segment boundary scan (3 kernels) ----------------
__global__ __launch_bounds__(256) void seg_count(const int* __restrict__ t,
                                                 int* __restrict__ blockCnt) {
  int i = blockIdx.x * 256 + threadIdx.x;
  bool flag = (i == 0) || (t[i] != t[i - 1]);
  unsigned long long b = __ballot(flag);
  __shared__ int wsum[4];
  int lane = threadIdx.x & 63, w = threadIdx.x >> 6;
  if (lane == 0) wsum[w] = __popcll(b);
  __syncthreads();
  if (threadIdx.x == 0)
    blockCnt[blockIdx.x] = wsum[0] + wsum[1] + wsum[2] + wsum[3];
}

__global__ void seg_scan(const int* __restrict__ blockCnt, int* __restrict__ blockOff,
                         int* __restrict__ starts) {
  if (threadIdx.x == 0) {
    int acc = 0;
    for (int b = 0; b < NTOK / 256; ++b) { blockOff[b] = acc; acc += blockCnt[b]; }
    starts[SEG] = NTOK;
  }
}

__global__ __launch_bounds__(256) void seg_emit(const int* __restrict__ t,
                                                const int* __restrict__ blockOff,
                                                int* __restrict__ starts,
                                                float* __restrict__ segt_out) {
  int i = blockIdx.x * 256 + threadIdx.x;
  bool flag = (i == 0) || (t[i] != t[i - 1]);
  unsigned long long b = __ballot(flag);
  int lane = threadIdx.x & 63, w = threadIdx.x >> 6;
  __shared__ int woff[4];
  if (lane == 0) woff[w] = __popcll(b);
  __syncthreads();
  if (threadIdx.x == 0) {
    int a = 0;
    for (int j = 0; j < 4; ++j) { int c = woff[j]; woff[j] = a; a += c; }
  }
  __syncthreads();
  if (flag) {
    int rank = blockOff[blockIdx.x] + woff[w] +
               __popcll(b & ((1ull << lane) - 1ull));
    starts[rank] = i;
    segt_out[rank] = (float)t[i];
  }
}

// ---------------- per-segment mean pool -> bf16 ----------------
__global__ __launch_bounds__(256) void pool_k(const float* __restrict__ feat,
                                              const int* __restrict__ starts,
                                              ushort_t* __restrict__ pooled) {
  int s = blockIdx.x;
  int rs = starts[s], re = starts[s + 1];
  float inv = 1.0f / (float)(re - rs);
  int tid = threadIdx.x;
  float a0 = 0.f, a1 = 0.f, a2 = 0.f;
  for (int r = rs; r < re; ++r) {
    const float* row = feat + (size_t)r * DDIM;
    a0 += row[tid]; a1 += row[tid + 256]; a2 += row[tid + 512];
  }
  size_t base = (size_t)s * DDIM;
  pooled[base + tid]       = f2bf(a0 * inv);
  pooled[base + tid + 256] = f2bf(a1 * inv);
  pooled[base + tid + 512] = f2bf(a2 * inv);
}

// ---------------- LayerNorm (f32 in -> bf16 out) ----------------
__global__ __launch_bounds__(256) void ln_k(const float* __restrict__ X,
                                            const float* __restrict__ gamma,
                                            const float* __restrict__ beta,
                                            ushort_t* __restrict__ Y) {
  int row = blockIdx.x;
  const float* x = X + (size_t)row * DDIM;
  int tid = threadIdx.x;
  float v0 = x[tid], v1 = x[tid + 256], v2 = x[tid + 512];
  __shared__ float sh[4];
  int lane = tid & 63, w = tid >> 6;

  float s = v0 + v1 + v2;
#pragma unroll
  for (int o = 32; o > 0; o >>= 1) s += __shfl_xor(s, o, 64);
  if (lane == 0) sh[w] = s;
  __syncthreads();
  float mu = (sh[0] + sh[1] + sh[2] + sh[3]) * (1.0f / DDIM);
  __syncthreads();

  float d0 = v0 - mu, d1 = v1 - mu, d2 = v2 - mu;
  float q = d0 * d0 + d1 * d1 + d2 * d2;
#pragma unroll
  for (int o = 32; o > 0; o >>= 1) q += __shfl_xor(q, o, 64);
  if (lane == 0) sh[w] = q;
  __syncthreads();
  float var = (sh[0] + sh[1] + sh[2] + sh[3]) * (1.0f / DDIM);
  float inv = rsqrtf(var + 1e-5f);

  size_t base = (size_t)row * DDIM;
  Y[base + tid]       = f2bf(d0 * inv * gamma[tid] + beta[tid]);
  Y[base + tid + 256] = f2bf(d1 * inv * gamma[tid + 256] + beta[tid + 256]);
  Y[base + tid + 512] = f2bf(d2 * inv * gamma[tid + 512] + beta[tid + 512]);
}

// ---------------- bf16 GEMM: C[M,N] = A[M,K] @ B[N,K]^T + bias ----------------
// m97 structure: 128x128 tile, BK=32, 256 threads (4 waves, 2x2), each wave 64x64
// via 4x4 frags of mfma_f32_16x16x32_bf16. global_load_lds width 16, linear LDS.
template <bool GELU>
__global__ __launch_bounds__(256) void gemm_bt(const ushort_t* __restrict__ A,
                                               const ushort_t* __restrict__ B,
                                               const float* __restrict__ bias,
                                               float* __restrict__ C,
                                               int M, int Nn, int K) {
  __shared__ __align__(16) ushort_t lA[128 * 32];
  __shared__ __align__(16) ushort_t lB[128 * 32];
  int tid = threadIdx.x;
  int w = tid >> 6, lane = tid & 63;
  int m0 = blockIdx.y * 128, n0 = blockIdx.x * 128;
  const ushort_t* Abase = A + (size_t)m0 * K;
  const ushort_t* Bbase = B + (size_t)n0 * K;

  f32x4 acc[4][4] = {};
  int wr = (w >> 1) * 64, wc = (w & 1) * 64;
  int fr = lane & 15;           // fragment row/col within 16
  int kc = (lane >> 4) * 8;     // k offset within BK

  // staging: load-index L in [0,512); wave w owns instruction slots 2w, 2w+1;
  // slot covers 64 lanes x 16B = 1024B of LDS (wave-uniform base + lane*16).
  int L0 = 2 * w * 64 + lane;
  int L1 = L0 + 64;
  int row0 = L0 >> 2, seg0 = L0 & 3;
  int row1 = L1 >> 2, seg1 = L1 & 3;

  for (int kt = 0; kt < K; kt += 32) {
    __builtin_amdgcn_global_load_lds(
        (const __attribute__((address_space(1))) void*)(Abase + (size_t)row0 * K + kt + seg0 * 8),
        (__attribute__((address_space(3))) void*)(lA + 2 * w * 512), 16, 0, 0);
    __builtin_amdgcn_global_load_lds(
        (const __attribute__((address_space(1))) void*)(Bbase + (size_t)row0 * K + kt + seg0 * 8),
        (__attribute__((address_space(3))) void*)(lB + 2 * w * 512), 16, 0, 0);
    __builtin_amdgcn_global_load_lds(
        (const __attribute__((address_space(1))) void*)(Abase + (size_t)row1 * K + kt + seg1 * 8),
        (__attribute__((address_space(3))) void*)(lA + (2 * w + 1) * 512), 16, 0, 0);
    __builtin_amdgcn_global_load_lds(
        (const __attribute__((address_space(1))) void*)(Bbase + (size_t)row1 * K + kt + seg1 * 8),
        (__attribute__((address_space(3))) void*)(lB + (2 * w + 1) * 512), 16, 0, 0);
    __syncthreads();   // drains vmcnt(0): tiles ready

    bf16x8 aF[4], bF[4];
#pragma unroll
    for (int f = 0; f < 4; ++f) {
      aF[f] = *(const bf16x8*)&lA[(wr + f * 16 + fr) * 32 + kc];
      bF[f] = *(const bf16x8*)&lB[(wc + f * 16 + fr) * 32 + kc];
    }
#pragma unroll
    for (int i = 0; i < 4; ++i)
#pragma unroll
      for (int j = 0; j < 4; ++j)
        acc[i][j] = __builtin_amdgcn_mfma_f32_16x16x32_bf16(aF[i], bF[j], acc[i][j], 0, 0, 0);
    __syncthreads();   // all reads done before next stage overwrites
  }

  // C/D layout: col = lane&15, row = (lane>>4)*4 + reg  [m89-verified]
  int crow = (lane >> 4) * 4, ccol = lane & 15;
#pragma unroll
  for (int j = 0; j < 4; ++j) {
    int gcol = n0 + wc + j * 16 + ccol;
    float bvv = bias[gcol];
#pragma unroll
    for (int i = 0; i < 4; ++i) {
      int grow = m0 + wr + i * 16 + crow;
#pragma unroll
      for (int r = 0; r < 4; ++r) {
        float v = acc[i][j][r] + bvv;
        if (GELU) v = 0.5f * v * (1.0f + erff(v * 0.70710678118654752f));
        C[(size_t)(grow + r) * Nn + gcol] = v;
      }
    }
  }
}

// ---------------- launch ----------------
extern "C" void kernel_launch(void* const* d_in, const int* in_sizes, int n_in,
                              void* d_out, int out_size, void* d_ws, size_t ws_size,
                              hipStream_t stream) {
  const float* features = (const float*)d_in[0];
  const int*   targets  = (const int*)d_in[1];
  // d_in[2] = num_words (device scalar) -- S is a compile-time constant here
  const float* Wd    = (const float*)d_in[3];
  const float* bd    = (const float*)d_in[4];
  const float* gamma = (const float*)d_in[5];
  const float* beta  = (const float*)d_in[6];
  const float* Wv    = (const float*)d_in[7];
  const float* bv    = (const float*)d_in[8];
  float* out = (float*)d_out;

  // workspace layout (~100.7 MB)
  ushort_t* wv_bf  = (ushort_t*)d_ws;                       // V*D bf16
  ushort_t* wd_bf  = wv_bf + (size_t)VOC * DDIM;            // D*D bf16
  ushort_t* pooled = wd_bf + (size_t)DDIM * DDIM;           // S*D bf16
  ushort_t* xln    = pooled + (size_t)SEG * DDIM;           // S*D bf16
  float*    dense  = (float*)(xln + (size_t)SEG * DDIM);    // S*D f32
  int*      starts = (int*)(dense + (size_t)SEG * DDIM);    // S+1
  int*      blockCnt = starts + SEG + 4;                    // NTOK/256
  int*      blockOff = blockCnt + NTOK / 256;               // NTOK/256

  // 1. weight conversions to bf16
  cvt_bf16<<<(VOC * DDIM / 4 + 255) / 256, 256, 0, stream>>>(
      (const float4*)Wv, (ushort4*)wv_bf, VOC * DDIM / 4);
  cvt_bf16<<<(DDIM * DDIM / 4 + 255) / 256, 256, 0, stream>>>(
      (const float4*)Wd, (ushort4*)wd_bf, DDIM * DDIM / 4);

  // 2. segment scan -> starts[], seg targets (as f32) straight into d_out tail
  seg_count<<<NTOK / 256, 256, 0, stream>>>(targets, blockCnt);
  seg_scan<<<1, 64, 0, stream>>>(blockCnt, blockOff, starts);
  seg_emit<<<NTOK / 256, 256, 0, stream>>>(targets, blockOff, starts,
                                           out + (size_t)SEG * VOC);

  // 3. mean pool -> bf16 [S,D]
  pool_k<<<SEG, 256, 0, stream>>>(features, starts, pooled);

  // 4. dense GEMM + bias + exact GELU -> f32 [S,D]
  gemm_bt<true><<<dim3(DDIM / 128, SEG / 128), 256, 0, stream>>>(
      pooled, wd_bf, bd, dense, SEG, DDIM, DDIM);

  // 5. LayerNorm -> bf16 [S,D]
  ln_k<<<SEG, 256, 0, stream>>>(dense, gamma, beta, xln);

  // 6. vocab GEMM + bias -> f32 logits [S,V]
  gemm_bt<false><<<dim3(VOC / 128, SEG / 128), 256, 0, stream>>>(
      xln, wv_bf, bv, out, SEG, VOC, DDIM);
}

// Round 2
// 792.855 us; speedup vs baseline: 1.0848x; 1.0848x over previous
//
#include <hip/hip_runtime.h>
#include <hip/hip_bf16.h>
#include <cstdint>

// Problem constants (from reference setup_inputs)
#define NTOK 65536
#define DDIM 768
#define VOC  32000
#define SEG  8192

typedef unsigned short ushort_t;
typedef __attribute__((ext_vector_type(8))) __bf16 bf16x8;
typedef __attribute__((ext_vector_type(4))) float  f32x4;

__device__ __forceinline__ ushort_t f2bf(float f) {
  uint32_t u = __builtin_bit_cast(uint32_t, f);
  return (ushort_t)((u + 0x7fffu + ((u >> 16) & 1u)) >> 16);
}

// ---------------- f32 -> bf16 conversion (vectorized) ----------------
__global__ __launch_bounds__(256) void cvt_bf16(const float4* __restrict__ in,
                                                ushort4* __restrict__ out, int n4) {
  int i = blockIdx.x * 256 + threadIdx.x;
  if (i >= n4) return;
  float4 v = in[i];
  ushort4 o;
  o.x = f2bf(v.x); o.y = f2bf(v.y); o.z = f2bf(v.z); o.w = f2bf(v.w);
  out[i] = o;
}

// ---------------- segment boundary scan (3 kernels) ----------------
__global__ __launch_bounds__(256) void seg_count(const int* __restrict__ t,
                                                 int* __restrict__ blockCnt) {
  int i = blockIdx.x * 256 + threadIdx.x;
  bool flag = (i == 0) || (t[i] != t[i - 1]);
  unsigned long long b = __ballot(flag);
  __shared__ int wsum[4];
  int lane = threadIdx.x & 63, w = threadIdx.x >> 6;
  if (lane == 0) wsum[w] = __popcll(b);
  __syncthreads();
  if (threadIdx.x == 0)
    blockCnt[blockIdx.x] = wsum[0] + wsum[1] + wsum[2] + wsum[3];
}

__global__ void seg_scan(const int* __restrict__ blockCnt, int* __restrict__ blockOff,
                         int* __restrict__ starts) {
  if (threadIdx.x == 0) {
    int acc = 0;
    for (int b = 0; b < NTOK / 256; ++b) { blockOff[b] = acc; acc += blockCnt[b]; }
    starts[SEG] = NTOK;
  }
}

__global__ __launch_bounds__(256) void seg_emit(const int* __restrict__ t,
                                                const int* __restrict__ blockOff,
                                                int* __restrict__ starts,
                                                float* __restrict__ segt_out) {
  int i = blockIdx.x * 256 + threadIdx.x;
  bool flag = (i == 0) || (t[i] != t[i - 1]);
  unsigned long long b = __ballot(flag);
  int lane = threadIdx.x & 63, w = threadIdx.x >> 6;
  __shared__ int woff[4];
  if (lane == 0) woff[w] = __popcll(b);
  __syncthreads();
  if (threadIdx.x == 0) {
    int a = 0;
    for (int j = 0; j < 4; ++j) { int c = woff[j]; woff[j] = a; a += c; }
  }
  __syncthreads();
  if (flag) {
    int rank = blockOff[blockIdx.x] + woff[w] +
               __popcll(b & ((1ull << lane) - 1ull));
    starts[rank] = i;
    segt_out[rank] = (float)t[i];
  }
}

// ---------------- per-segment mean pool -> bf16 ----------------
__global__ __launch_bounds__(256) void pool_k(const float* __restrict__ feat,
                                              const int* __restrict__ starts,
                                              ushort_t* __restrict__ pooled) {
  int s = blockIdx.x;
  int rs = starts[s], re = starts[s + 1];
  float inv = 1.0f / (float)(re - rs);
  int tid = threadIdx.x;
  float a0 = 0.f, a1 = 0.f, a2 = 0.f;
  for (int r = rs; r < re; ++r) {
    const float* row = feat + (size_t)r * DDIM;
    a0 += row[tid]; a1 += row[tid + 256]; a2 += row[tid + 512];
  }
  size_t base = (size_t)s * DDIM;
  pooled[base + tid]       = f2bf(a0 * inv);
  pooled[base + tid + 256] = f2bf(a1 * inv);
  pooled[base + tid + 512] = f2bf(a2 * inv);
}

// ---------------- LayerNorm (f32 in -> bf16 out) ----------------
__global__ __launch_bounds__(256) void ln_k(const float* __restrict__ X,
                                            const float* __restrict__ gamma,
                                            const float* __restrict__ beta,
                                            ushort_t* __restrict__ Y) {
  int row = blockIdx.x;
  const float* x = X + (size_t)row * DDIM;
  int tid = threadIdx.x;
  float v0 = x[tid], v1 = x[tid + 256], v2 = x[tid + 512];
  __shared__ float sh[4];
  int lane = tid & 63, w = tid >> 6;

  float s = v0 + v1 + v2;
#pragma unroll
  for (int o = 32; o > 0; o >>= 1) s += __shfl_xor(s, o, 64);
  if (lane == 0) sh[w] = s;
  __syncthreads();
  float mu = (sh[0] + sh[1] + sh[2] + sh[3]) * (1.0f / DDIM);
  __syncthreads();

  float d0 = v0 - mu, d1 = v1 - mu, d2 = v2 - mu;
  float q = d0 * d0 + d1 * d1 + d2 * d2;
#pragma unroll
  for (int o = 32; o > 0; o >>= 1) q += __shfl_xor(q, o, 64);
  if (lane == 0) sh[w] = q;
  __syncthreads();
  float var = (sh[0] + sh[1] + sh[2] + sh[3]) * (1.0f / DDIM);
  float inv = rsqrtf(var + 1e-5f);

  size_t base = (size_t)row * DDIM;
  Y[base + tid]       = f2bf(d0 * inv * gamma[tid] + beta[tid]);
  Y[base + tid + 256] = f2bf(d1 * inv * gamma[tid + 256] + beta[tid + 256]);
  Y[base + tid + 512] = f2bf(d2 * inv * gamma[tid + 512] + beta[tid + 512]);
}

// ---------------- 256x256 bf16 GEMM, counted-vmcnt pipeline ----------------
// C[M,N] = A[M,K] @ B[N,K]^T + bias (optional exact GELU).
// 8 waves (2Mx4N), per-wave 128x64 out via 8x4 frags of mfma_f32_16x16x32_bf16.
// BK=32, 4 LDS buffers (4 x (A 16KB + B 16KB) = 128 KiB), prefetch depth 2:
// while computing tile t, tiles t+1,t+2 are in flight, tile t+3 is issued.
// Steady-state wait = vmcnt(8) (never drains; T4). LDS XOR-swizzled (T2) via
// pre-swizzled global source (rule #21). Raw s_barrier (1/tile). T5 setprio.
template <bool GELU>
__global__ __launch_bounds__(512, 2) void gemm256(const ushort_t* __restrict__ A,
                                                  const ushort_t* __restrict__ B,
                                                  const float* __restrict__ bias,
                                                  float* __restrict__ C,
                                                  int M, int Nn, int K) {
  __shared__ __align__(16) char lds[131072];
  const int tid = threadIdx.x, w = tid >> 6, lane = tid & 63;
  const int NT = K >> 5;

  // T1: bijective XCD swizzle over linear grid (nwg % 8 == 0 by construction)
  const int nbx = Nn >> 8;
  const int nby = M >> 8;
  const int nwg = nbx * nby;
  const int bid = (int)blockIdx.x;
  const int swz = (bid & 7) * (nwg >> 3) + (bid >> 3);
  const int by = swz / nbx, bx = swz - by * nbx;
  const int m0 = by << 8, n0 = bx << 8;

  // ---- staging addresses (pre-swizzled global source; linear LDS dest) ----
  // slot-0 LDS dest byte (within 16KB region): xd = w*1024 + lane*16 (rows 0..127)
  // slot-1 = xd + 8192 (rows 128..255, same col, same swizzle bits)
  const int xd = w * 1024 + lane * 16;
  const int xl = xd ^ (((xd >> 7) & 3) << 4);   // swizzle: XOR bits4-5 with bits7-8
  const int srow = xd >> 6;                     // row unchanged by swizzle
  const int scol = (xl & 63) >> 1;              // element col 0..31 (mult of 8)
  const ushort_t* gA = A + (size_t)(m0 + srow) * K + scol;
  const ushort_t* gB = B + (size_t)(n0 + srow) * K + scol;
  const size_t halfK = (size_t)128 * K;

  // ---- ds_read addresses (swizzled read side) ----
  const int fr = lane & 15;
  const int cBy = (lane >> 4) << 4;             // k-chunk byte 0/16/32/48
  const int wr = (w >> 2) << 7;                 // wave M-offset: 0 or 128
  const int wc = (w & 3) << 6;                  // wave N-offset: 0/64/128/192
  const int sx = ((fr >> 1) & 3) << 4;          // swizzle bits (f-independent)
  const int rdA = ((((wr + fr) << 6) + cBy) ^ sx);
  const int rdB = ((((wc + fr) << 6) + cBy) ^ sx) + 16384;

  f32x4 acc[8][4] = {};

#define STAGE(tt)                                                                        \
  do {                                                                                   \
    char* bb = lds + ((tt) & 3) * 32768;                                                 \
    const size_t ko = (size_t)(tt) * 32;                                                 \
    __builtin_amdgcn_global_load_lds(                                                    \
        (const __attribute__((address_space(1))) void*)(gA + ko),                        \
        (__attribute__((address_space(3))) void*)(bb + w * 1024), 16, 0, 0);             \
    __builtin_amdgcn_global_load_lds(                                                    \
        (const __attribute__((address_space(1))) void*)(gA + halfK + ko),                \
        (__attribute__((address_space(3))) void*)(bb + (w + 8) * 1024), 16, 0, 0);       \
    __builtin_amdgcn_global_load_lds(                                                    \
        (const __attribute__((address_space(1))) void*)(gB + ko),                        \
        (__attribute__((address_space(3))) void*)(bb + 16384 + w * 1024), 16, 0, 0);     \
    __builtin_amdgcn_global_load_lds(                                                    \
        (const __attribute__((address_space(1))) void*)(gB + halfK + ko),                \
        (__attribute__((address_space(3))) void*)(bb + 16384 + (w + 8) * 1024), 16, 0, 0);\
  } while (0)

  // prologue: stage tiles 0..2 (12 loads in flight), wait for tile 0 only
  if (0 < NT) STAGE(0);
  if (1 < NT) STAGE(1);
  if (2 < NT) STAGE(2);
  if (NT > 2) { asm volatile("s_waitcnt vmcnt(8)" ::: "memory"); }
  else        { asm volatile("s_waitcnt vmcnt(0)" ::: "memory"); }
  __builtin_amdgcn_s_barrier();

  for (int t = 0; t < NT; ++t) {
    if (t + 3 < NT) STAGE(t + 3);   // issue BEFORE ds_read+MFMA

    const char* tb = lds + (t & 3) * 32768;
    bf16x8 aF[8], bF[4];
#pragma unroll
    for (int f = 0; f < 8; ++f) aF[f] = *(const bf16x8*)(tb + rdA + f * 1024);
#pragma unroll
    for (int g = 0; g < 4; ++g) bF[g] = *(const bf16x8*)(tb + rdB + g * 1024);

    __builtin_amdgcn_s_setprio(1);
#pragma unroll
    for (int f = 0; f < 8; ++f)
#pragma unroll
      for (int g = 0; g < 4; ++g)
        acc[f][g] = __builtin_amdgcn_mfma_f32_16x16x32_bf16(aF[f], bF[g], acc[f][g], 0, 0, 0);
    __builtin_amdgcn_s_setprio(0);

    // counted wait: tile t+1 must be resident; keep t+2,t+3 in flight
    if (t + 4 <= NT)      { asm volatile("s_waitcnt vmcnt(8)" ::: "memory"); }
    else if (t + 3 == NT) { asm volatile("s_waitcnt vmcnt(4)" ::: "memory"); }
    else                  { asm volatile("s_waitcnt vmcnt(0)" ::: "memory"); }
    __builtin_amdgcn_s_barrier();
  }
#undef STAGE

  // epilogue: C/D layout col=lane&15, row=(lane>>4)*4+reg  [m89-verified]
  const int crow = (lane >> 4) << 2, ccol = lane & 15;
#pragma unroll
  for (int g = 0; g < 4; ++g) {
    const int gcol = n0 + wc + g * 16 + ccol;
    const float bvv = bias[gcol];
#pragma unroll
    for (int f = 0; f < 8; ++f) {
      const int grow = m0 + wr + f * 16 + crow;
#pragma unroll
      for (int r = 0; r < 4; ++r) {
        float v = acc[f][g][r] + bvv;
        if (GELU) v = 0.5f * v * (1.0f + erff(v * 0.70710678118654752f));
        C[(size_t)(grow + r) * Nn + gcol] = v;
      }
    }
  }
}

// ---------------- launch ----------------
extern "C" void kernel_launch(void* const* d_in, const int* in_sizes, int n_in,
                              void* d_out, int out_size, void* d_ws, size_t ws_size,
                              hipStream_t stream) {
  const float* features = (const float*)d_in[0];
  const int*   targets  = (const int*)d_in[1];
  // d_in[2] = num_words (device scalar) -- S is a compile-time constant here
  const float* Wd    = (const float*)d_in[3];
  const float* bd    = (const float*)d_in[4];
  const float* gamma = (const float*)d_in[5];
  const float* beta  = (const float*)d_in[6];
  const float* Wv    = (const float*)d_in[7];
  const float* bv    = (const float*)d_in[8];
  float* out = (float*)d_out;

  // workspace layout (~100.7 MB)
  ushort_t* wv_bf  = (ushort_t*)d_ws;                       // V*D bf16
  ushort_t* wd_bf  = wv_bf + (size_t)VOC * DDIM;            // D*D bf16
  ushort_t* pooled = wd_bf + (size_t)DDIM * DDIM;           // S*D bf16
  ushort_t* xln    = pooled + (size_t)SEG * DDIM;           // S*D bf16
  float*    dense  = (float*)(xln + (size_t)SEG * DDIM);    // S*D f32
  int*      starts = (int*)(dense + (size_t)SEG * DDIM);    // S+1
  int*      blockCnt = starts + SEG + 4;                    // NTOK/256
  int*      blockOff = blockCnt + NTOK / 256;               // NTOK/256

  // 1. weight conversions to bf16
  cvt_bf16<<<(VOC * DDIM / 4 + 255) / 256, 256, 0, stream>>>(
      (const float4*)Wv, (ushort4*)wv_bf, VOC * DDIM / 4);
  cvt_bf16<<<(DDIM * DDIM / 4 + 255) / 256, 256, 0, stream>>>(
      (const float4*)Wd, (ushort4*)wd_bf, DDIM * DDIM / 4);

  // 2. segment scan -> starts[], seg targets (as f32) straight into d_out tail
  seg_count<<<NTOK / 256, 256, 0, stream>>>(targets, blockCnt);
  seg_scan<<<1, 64, 0, stream>>>(blockCnt, blockOff, starts);
  seg_emit<<<NTOK / 256, 256, 0, stream>>>(targets, blockOff, starts,
                                           out + (size_t)SEG * VOC);

  // 3. mean pool -> bf16 [S,D]
  pool_k<<<SEG, 256, 0, stream>>>(features, starts, pooled);

  // 4. dense GEMM + bias + exact GELU -> f32 [S,D]  (grid 96 blocks, 96%8==0)
  gemm256<true><<<(SEG / 256) * (DDIM / 256), 512, 0, stream>>>(
      pooled, wd_bf, bd, dense, SEG, DDIM, DDIM);

  // 5. LayerNorm -> bf16 [S,D]
  ln_k<<<SEG, 256, 0, stream>>>(dense, gamma, beta, xln);

  // 6. vocab GEMM + bias -> f32 logits [S,V]  (grid 4000 blocks, 4000%8==0)
  gemm256<false><<<(SEG / 256) * (VOC / 256), 512, 0, stream>>>(
      xln, wv_bf, bv, out, SEG, VOC, DDIM);
}